// Round 1
// baseline (3029.103 us; speedup 1.0000x reference)
//
#include <hip/hip_runtime.h>
#include <hip/hip_bf16.h>

// Problem: B=8, S=2048, H=1024
//   xw     = x @ W                  [B,S,H]   (fp32)
//   scores = xw @ x^T               [B,S,S]
//   attn   = softmax(scores, -1)    [B,S,S]   -> output 1
//   ctx    = attn @ x               [B,S,H]   -> output 0
//
// Round 0: all-fp32 correctness baseline. 64x64 tiles, 4x4 per thread,
// both LDS operands stored K-contiguous (row stride 20 floats keeps float4
// alignment) so the inner loop is ds_read_b128. scores are written straight
// into the attn region of d_out and softmaxed in place; only XW lives in d_ws.

#define BB 8
#define SS 2048
#define HH 1024

// ---------------------------------------------------------------- gemm: XW = X @ W
__global__ __launch_bounds__(256) void gemm_xw(const float* __restrict__ X,
                                               const float* __restrict__ W,
                                               float* __restrict__ XW) {
    const int b = blockIdx.z, i0 = blockIdx.y * 64, n0 = blockIdx.x * 64;
    const float* A = X + (size_t)b * SS * HH;
    __shared__ float As[64][20];   // [m][k], k contiguous
    __shared__ float Bs[64][20];   // [n][k], k contiguous (W transposed on store)
    const int tid = threadIdx.x;
    const int tx = tid & 15, ty = tid >> 4;
    float acc[4][4] = {};
    for (int k0 = 0; k0 < HH; k0 += 16) {
        {   // A tile 64x16
            const int k_in = tid & 15, m_in = tid >> 4;
#pragma unroll
            for (int q = 0; q < 4; q++)
                As[m_in + 16 * q][k_in] = A[(size_t)(i0 + m_in + 16 * q) * HH + (k0 + k_in)];
        }
        {   // W tile 16x64, transposed into Bs[n][k]
            const int n_in = tid & 63, k_in = tid >> 6;
#pragma unroll
            for (int q = 0; q < 4; q++)
                Bs[n_in][k_in + 4 * q] = W[(size_t)(k0 + k_in + 4 * q) * HH + (n0 + n_in)];
        }
        __syncthreads();
#pragma unroll
        for (int kk = 0; kk < 16; kk += 4) {
            float4 a4[4], b4[4];
#pragma unroll
            for (int r = 0; r < 4; r++) a4[r] = *(const float4*)&As[ty + 16 * r][kk];
#pragma unroll
            for (int c = 0; c < 4; c++) b4[c] = *(const float4*)&Bs[tx + 16 * c][kk];
#pragma unroll
            for (int r = 0; r < 4; r++)
#pragma unroll
                for (int c = 0; c < 4; c++)
                    acc[r][c] += a4[r].x * b4[c].x + a4[r].y * b4[c].y +
                                 a4[r].z * b4[c].z + a4[r].w * b4[c].w;
        }
        __syncthreads();
    }
    float* Cb = XW + (size_t)b * SS * HH;
#pragma unroll
    for (int r = 0; r < 4; r++)
#pragma unroll
        for (int c = 0; c < 4; c++)
            Cb[(size_t)(i0 + ty + 16 * r) * HH + (n0 + tx + 16 * c)] = acc[r][c];
}

// ------------------------------------------------- gemm (NT): SC = XW @ X^T per batch
__global__ __launch_bounds__(256) void gemm_scores(const float* __restrict__ XW,
                                                   const float* __restrict__ X,
                                                   float* __restrict__ SC) {
    const int b = blockIdx.z, i0 = blockIdx.y * 64, j0 = blockIdx.x * 64;
    const float* A  = XW + (size_t)b * SS * HH;
    const float* Bm = X  + (size_t)b * SS * HH;
    __shared__ float As[64][20];
    __shared__ float Bs[64][20];
    const int tid = threadIdx.x;
    const int tx = tid & 15, ty = tid >> 4;
    float acc[4][4] = {};
    for (int k0 = 0; k0 < HH; k0 += 16) {
        const int k_in = tid & 15, m_in = tid >> 4;
#pragma unroll
        for (int q = 0; q < 4; q++)
            As[m_in + 16 * q][k_in] = A[(size_t)(i0 + m_in + 16 * q) * HH + (k0 + k_in)];
#pragma unroll
        for (int q = 0; q < 4; q++)
            Bs[m_in + 16 * q][k_in] = Bm[(size_t)(j0 + m_in + 16 * q) * HH + (k0 + k_in)];
        __syncthreads();
#pragma unroll
        for (int kk = 0; kk < 16; kk += 4) {
            float4 a4[4], b4[4];
#pragma unroll
            for (int r = 0; r < 4; r++) a4[r] = *(const float4*)&As[ty + 16 * r][kk];
#pragma unroll
            for (int c = 0; c < 4; c++) b4[c] = *(const float4*)&Bs[tx + 16 * c][kk];
#pragma unroll
            for (int r = 0; r < 4; r++)
#pragma unroll
                for (int c = 0; c < 4; c++)
                    acc[r][c] += a4[r].x * b4[c].x + a4[r].y * b4[c].y +
                                 a4[r].z * b4[c].z + a4[r].w * b4[c].w;
        }
        __syncthreads();
    }
    float* Cb = SC + (size_t)b * SS * SS;
#pragma unroll
    for (int r = 0; r < 4; r++)
#pragma unroll
        for (int c = 0; c < 4; c++)
            Cb[(size_t)(i0 + ty + 16 * r) * SS + (j0 + tx + 16 * c)] = acc[r][c];
}

// ------------------------------------------------------- softmax in place, 1 block/row
__global__ __launch_bounds__(256) void softmax_rows(float* __restrict__ P) {
    const size_t row = blockIdx.x;
    float4* p4 = (float4*)(P + row * SS);
    const int tid = threadIdx.x;
    float4 v0 = p4[tid], v1 = p4[tid + 256];
    float m = fmaxf(fmaxf(fmaxf(v0.x, v0.y), fmaxf(v0.z, v0.w)),
                    fmaxf(fmaxf(v1.x, v1.y), fmaxf(v1.z, v1.w)));
#pragma unroll
    for (int off = 32; off; off >>= 1) m = fmaxf(m, __shfl_xor(m, off));
    __shared__ float red[4];
    const int wid = tid >> 6, lane = tid & 63;
    if (lane == 0) red[wid] = m;
    __syncthreads();
    m = fmaxf(fmaxf(red[0], red[1]), fmaxf(red[2], red[3]));
    v0.x = __expf(v0.x - m); v0.y = __expf(v0.y - m);
    v0.z = __expf(v0.z - m); v0.w = __expf(v0.w - m);
    v1.x = __expf(v1.x - m); v1.y = __expf(v1.y - m);
    v1.z = __expf(v1.z - m); v1.w = __expf(v1.w - m);
    float s = v0.x + v0.y + v0.z + v0.w + v1.x + v1.y + v1.z + v1.w;
#pragma unroll
    for (int off = 32; off; off >>= 1) s += __shfl_xor(s, off);
    __syncthreads();             // red[] reuse
    if (lane == 0) red[wid] = s;
    __syncthreads();
    s = red[0] + red[1] + red[2] + red[3];
    const float inv = 1.0f / s;
    v0.x *= inv; v0.y *= inv; v0.z *= inv; v0.w *= inv;
    v1.x *= inv; v1.y *= inv; v1.z *= inv; v1.w *= inv;
    p4[tid] = v0;
    p4[tid + 256] = v1;
}

// ------------------------------------------------- gemm (NN): CTX = ATTN @ X per batch
__global__ __launch_bounds__(256) void gemm_ctx(const float* __restrict__ AT,
                                                const float* __restrict__ X,
                                                float* __restrict__ C) {
    const int b = blockIdx.z, i0 = blockIdx.y * 64, h0 = blockIdx.x * 64;
    const float* A  = AT + (size_t)b * SS * SS;
    const float* Bm = X  + (size_t)b * SS * HH;
    __shared__ float As[64][20];
    __shared__ float Bs[64][20];   // [h][j], transposed on store
    const int tid = threadIdx.x;
    const int tx = tid & 15, ty = tid >> 4;
    float acc[4][4] = {};
    for (int k0 = 0; k0 < SS; k0 += 16) {
        {
            const int k_in = tid & 15, m_in = tid >> 4;
#pragma unroll
            for (int q = 0; q < 4; q++)
                As[m_in + 16 * q][k_in] = A[(size_t)(i0 + m_in + 16 * q) * SS + (k0 + k_in)];
        }
        {
            const int n_in = tid & 63, k_in = tid >> 6;
#pragma unroll
            for (int q = 0; q < 4; q++)
                Bs[n_in][k_in + 4 * q] = Bm[(size_t)(k0 + k_in + 4 * q) * HH + (h0 + n_in)];
        }
        __syncthreads();
#pragma unroll
        for (int kk = 0; kk < 16; kk += 4) {
            float4 a4[4], b4[4];
#pragma unroll
            for (int r = 0; r < 4; r++) a4[r] = *(const float4*)&As[ty + 16 * r][kk];
#pragma unroll
            for (int c = 0; c < 4; c++) b4[c] = *(const float4*)&Bs[tx + 16 * c][kk];
#pragma unroll
            for (int r = 0; r < 4; r++)
#pragma unroll
                for (int c = 0; c < 4; c++)
                    acc[r][c] += a4[r].x * b4[c].x + a4[r].y * b4[c].y +
                                 a4[r].z * b4[c].z + a4[r].w * b4[c].w;
        }
        __syncthreads();
    }
    float* Cb = C + (size_t)b * SS * HH;
#pragma unroll
    for (int r = 0; r < 4; r++)
#pragma unroll
        for (int c = 0; c < 4; c++)
            Cb[(size_t)(i0 + ty + 16 * r) * HH + (h0 + tx + 16 * c)] = acc[r][c];
}

extern "C" void kernel_launch(void* const* d_in, const int* in_sizes, int n_in,
                              void* d_out, int out_size, void* d_ws, size_t ws_size,
                              hipStream_t stream) {
    const float* X = (const float*)d_in[0];   // [8,2048,1024] fp32
    const float* W = (const float*)d_in[1];   // [1024,1024]  fp32
    float* ctx  = (float*)d_out;                          // [8,2048,1024]
    float* attn = ctx + (size_t)BB * SS * HH;             // [8,2048,2048]
    float* XW   = (float*)d_ws;                           // 64 MiB scratch

    dim3 blk(256);
    gemm_xw    <<<dim3(HH / 64, SS / 64, BB), blk, 0, stream>>>(X, W, XW);
    gemm_scores<<<dim3(SS / 64, SS / 64, BB), blk, 0, stream>>>(XW, X, attn);
    softmax_rows<<<dim3(BB * SS), blk, 0, stream>>>(attn);
    gemm_ctx   <<<dim3(HH / 64, SS / 64, BB), blk, 0, stream>>>(attn, X, ctx);
}

// Round 2
// 2115.929 us; speedup vs baseline: 1.4316x; 1.4316x over previous
//
#include <hip/hip_runtime.h>
#include <hip/hip_bf16.h>

// B=8, S=2048, H=1024
//   xw     = x @ W        (fp32 tiled GEMM, unchanged)        -> d_ws
//   scores = xw @ x^T     (fp32 tiled GEMM, unchanged)        -> attn region of d_out
//   attn   = softmax      (in place; ALSO emits bf16 copy)    -> d_out + d_ws
//   ctx    = attn @ x     (bf16 MFMA, m97 structure, NT via pre-transposed xT)
//
// ws layout: [0,32MB) xT bf16 [B,H,S] ; [32MB,96MB) XW fp32, reused as attn_bf16
// after gemm_scores (XW dead once scores are written).

#define BB 8
#define SS 2048
#define HH 1024

typedef __attribute__((ext_vector_type(8))) short bf16x8;
typedef __attribute__((ext_vector_type(4))) float f32x4;

__device__ __forceinline__ void async_load16(const void* gsrc, void* ldst) {
    typedef const unsigned int __attribute__((address_space(1)))* gp_t;
    typedef unsigned int __attribute__((address_space(3)))* lp_t;
    __builtin_amdgcn_global_load_lds((gp_t)gsrc, (lp_t)ldst, 16, 0, 0);
}

__device__ __forceinline__ unsigned short f2b(float f) {
    __hip_bfloat16 h = __float2bfloat16(f);
    return *(unsigned short*)&h;
}

// ---------------------------------------------------------------- gemm: XW = X @ W (fp32)
__global__ __launch_bounds__(256) void gemm_xw(const float* __restrict__ X,
                                               const float* __restrict__ W,
                                               float* __restrict__ XW) {
    const int b = blockIdx.z, i0 = blockIdx.y * 64, n0 = blockIdx.x * 64;
    const float* A = X + (size_t)b * SS * HH;
    __shared__ float As[64][20];
    __shared__ float Bs[64][20];
    const int tid = threadIdx.x;
    const int tx = tid & 15, ty = tid >> 4;
    float acc[4][4] = {};
    for (int k0 = 0; k0 < HH; k0 += 16) {
        {
            const int k_in = tid & 15, m_in = tid >> 4;
#pragma unroll
            for (int q = 0; q < 4; q++)
                As[m_in + 16 * q][k_in] = A[(size_t)(i0 + m_in + 16 * q) * HH + (k0 + k_in)];
        }
        {
            const int n_in = tid & 63, k_in = tid >> 6;
#pragma unroll
            for (int q = 0; q < 4; q++)
                Bs[n_in][k_in + 4 * q] = W[(size_t)(k0 + k_in + 4 * q) * HH + (n0 + n_in)];
        }
        __syncthreads();
#pragma unroll
        for (int kk = 0; kk < 16; kk += 4) {
            float4 a4[4], b4[4];
#pragma unroll
            for (int r = 0; r < 4; r++) a4[r] = *(const float4*)&As[ty + 16 * r][kk];
#pragma unroll
            for (int c = 0; c < 4; c++) b4[c] = *(const float4*)&Bs[tx + 16 * c][kk];
#pragma unroll
            for (int r = 0; r < 4; r++)
#pragma unroll
                for (int c = 0; c < 4; c++)
                    acc[r][c] += a4[r].x * b4[c].x + a4[r].y * b4[c].y +
                                 a4[r].z * b4[c].z + a4[r].w * b4[c].w;
        }
        __syncthreads();
    }
    float* Cb = XW + (size_t)b * SS * HH;
#pragma unroll
    for (int r = 0; r < 4; r++)
#pragma unroll
        for (int c = 0; c < 4; c++)
            Cb[(size_t)(i0 + ty + 16 * r) * HH + (n0 + tx + 16 * c)] = acc[r][c];
}

// ------------------------------------------------- gemm (NT): SC = XW @ X^T (fp32)
__global__ __launch_bounds__(256) void gemm_scores(const float* __restrict__ XW,
                                                   const float* __restrict__ X,
                                                   float* __restrict__ SC) {
    const int b = blockIdx.z, i0 = blockIdx.y * 64, j0 = blockIdx.x * 64;
    const float* A  = XW + (size_t)b * SS * HH;
    const float* Bm = X  + (size_t)b * SS * HH;
    __shared__ float As[64][20];
    __shared__ float Bs[64][20];
    const int tid = threadIdx.x;
    const int tx = tid & 15, ty = tid >> 4;
    float acc[4][4] = {};
    for (int k0 = 0; k0 < HH; k0 += 16) {
        const int k_in = tid & 15, m_in = tid >> 4;
#pragma unroll
        for (int q = 0; q < 4; q++)
            As[m_in + 16 * q][k_in] = A[(size_t)(i0 + m_in + 16 * q) * HH + (k0 + k_in)];
#pragma unroll
        for (int q = 0; q < 4; q++)
            Bs[m_in + 16 * q][k_in] = Bm[(size_t)(j0 + m_in + 16 * q) * HH + (k0 + k_in)];
        __syncthreads();
#pragma unroll
        for (int kk = 0; kk < 16; kk += 4) {
            float4 a4[4], b4[4];
#pragma unroll
            for (int r = 0; r < 4; r++) a4[r] = *(const float4*)&As[ty + 16 * r][kk];
#pragma unroll
            for (int c = 0; c < 4; c++) b4[c] = *(const float4*)&Bs[tx + 16 * c][kk];
#pragma unroll
            for (int r = 0; r < 4; r++)
#pragma unroll
                for (int c = 0; c < 4; c++)
                    acc[r][c] += a4[r].x * b4[c].x + a4[r].y * b4[c].y +
                                 a4[r].z * b4[c].z + a4[r].w * b4[c].w;
        }
        __syncthreads();
    }
    float* Cb = SC + (size_t)b * SS * SS;
#pragma unroll
    for (int r = 0; r < 4; r++)
#pragma unroll
        for (int c = 0; c < 4; c++)
            Cb[(size_t)(i0 + ty + 16 * r) * SS + (j0 + tx + 16 * c)] = acc[r][c];
}

// --------------------------- softmax in place (fp32) + bf16 copy for the MFMA ctx GEMM
__global__ __launch_bounds__(256) void softmax_rows(float* __restrict__ P,
                                                    unsigned short* __restrict__ Pb) {
    const size_t row = blockIdx.x;
    float4* p4 = (float4*)(P + row * SS);
    const int tid = threadIdx.x;
    float4 v0 = p4[tid], v1 = p4[tid + 256];
    float m = fmaxf(fmaxf(fmaxf(v0.x, v0.y), fmaxf(v0.z, v0.w)),
                    fmaxf(fmaxf(v1.x, v1.y), fmaxf(v1.z, v1.w)));
#pragma unroll
    for (int off = 32; off; off >>= 1) m = fmaxf(m, __shfl_xor(m, off));
    __shared__ float red[4];
    const int wid = tid >> 6, lane = tid & 63;
    if (lane == 0) red[wid] = m;
    __syncthreads();
    m = fmaxf(fmaxf(red[0], red[1]), fmaxf(red[2], red[3]));
    v0.x = __expf(v0.x - m); v0.y = __expf(v0.y - m);
    v0.z = __expf(v0.z - m); v0.w = __expf(v0.w - m);
    v1.x = __expf(v1.x - m); v1.y = __expf(v1.y - m);
    v1.z = __expf(v1.z - m); v1.w = __expf(v1.w - m);
    float s = v0.x + v0.y + v0.z + v0.w + v1.x + v1.y + v1.z + v1.w;
#pragma unroll
    for (int off = 32; off; off >>= 1) s += __shfl_xor(s, off);
    __syncthreads();
    if (lane == 0) red[wid] = s;
    __syncthreads();
    s = red[0] + red[1] + red[2] + red[3];
    const float inv = 1.0f / s;
    v0.x *= inv; v0.y *= inv; v0.z *= inv; v0.w *= inv;
    v1.x *= inv; v1.y *= inv; v1.z *= inv; v1.w *= inv;
    p4[tid] = v0;
    p4[tid + 256] = v1;
    ushort4* b4 = (ushort4*)(Pb + row * SS);
    ushort4 u0 = { f2b(v0.x), f2b(v0.y), f2b(v0.z), f2b(v0.w) };
    ushort4 u1 = { f2b(v1.x), f2b(v1.y), f2b(v1.z), f2b(v1.w) };
    b4[tid] = u0;
    b4[tid + 256] = u1;
}

// --------------------------------- x [B,S,H] fp32 -> xT [B,H,S] bf16 (for NT ctx GEMM)
__global__ __launch_bounds__(256) void transpose_cvt(const float* __restrict__ X,
                                                     unsigned short* __restrict__ XT) {
    const int b = blockIdx.z;
    const int t0 = blockIdx.y * 64;   // S tile
    const int h0 = blockIdx.x * 64;   // H tile
    __shared__ float tile[64][65];
    const float* Xb = X + (size_t)b * SS * HH;
    unsigned short* Tb = XT + (size_t)b * HH * SS;
#pragma unroll
    for (int q = 0; q < 16; q++) {
        int idx = q * 256 + threadIdx.x;
        int r = idx >> 6, c = idx & 63;
        tile[r][c] = Xb[(size_t)(t0 + r) * HH + h0 + c];
    }
    __syncthreads();
#pragma unroll
    for (int q = 0; q < 16; q++) {
        int idx = q * 256 + threadIdx.x;
        int r = idx >> 6, c = idx & 63;          // r = h idx, c = t idx
        Tb[(size_t)(h0 + r) * SS + t0 + c] = f2b(tile[c][r]);
    }
}

// ----------------- ctx = attn @ x  ==  A[S,S](bf16) x Bt[H,S](bf16), NT, MFMA 16x16x32
// 128x128 tile, BK=32, 4 waves in 2x2, 4x4 frags/wave, global_load_lds width-16 staging.
__global__ __launch_bounds__(256) void gemm_ctx_mfma(const unsigned short* __restrict__ Ab,
                                                     const unsigned short* __restrict__ Bt,
                                                     float* __restrict__ C) {
    const int b = blockIdx.z;
    const int i0 = blockIdx.y * 128;           // M (S dim)
    const int n0 = blockIdx.x * 128;           // N (H dim)
    const unsigned short* A = Ab + (size_t)b * SS * SS;
    const unsigned short* B = Bt + (size_t)b * HH * SS;

    __shared__ __align__(16) unsigned short As[128 * 32];
    __shared__ __align__(16) unsigned short Bs[128 * 32];

    const int tid = threadIdx.x;
    const int wave = tid >> 6, lane = tid & 63;
    const int m16 = lane & 15, quad = lane >> 4;
    const int wy = wave >> 1, wx = wave & 1;

    const int rowA = tid >> 2;     // 0..63 (q adds 64)
    const int kq = tid & 3;        // 16B chunk within a 32-elem row

    f32x4 acc[4][4] = {};

    for (int k0 = 0; k0 < SS; k0 += 32) {
        // stage A: rows i0..i0+127, k0..k0+31 ; LDS chunk c = row*4 + kq, HW adds lane*16
        async_load16(A + (size_t)(i0 + rowA) * SS + k0 + kq * 8,
                     (char*)As + wave * 1024);
        async_load16(A + (size_t)(i0 + 64 + rowA) * SS + k0 + kq * 8,
                     (char*)As + 4096 + wave * 1024);
        async_load16(B + (size_t)(n0 + rowA) * SS + k0 + kq * 8,
                     (char*)Bs + wave * 1024);
        async_load16(B + (size_t)(n0 + 64 + rowA) * SS + k0 + kq * 8,
                     (char*)Bs + 4096 + wave * 1024);
        __syncthreads();

        const unsigned short* pA = As + (wy * 64 + m16) * 32 + quad * 8;
        const unsigned short* pB = Bs + (wx * 64 + m16) * 32 + quad * 8;
        bf16x8 af[4], bfr[4];
#pragma unroll
        for (int r = 0; r < 4; r++) af[r] = *(const bf16x8*)(pA + r * 16 * 32);
#pragma unroll
        for (int c = 0; c < 4; c++) bfr[c] = *(const bf16x8*)(pB + c * 16 * 32);
#pragma unroll
        for (int r = 0; r < 4; r++)
#pragma unroll
            for (int c = 0; c < 4; c++)
                acc[r][c] = __builtin_amdgcn_mfma_f32_16x16x32_bf16(af[r], bfr[c], acc[r][c], 0, 0, 0);
        __syncthreads();
    }

    float* Cb = C + (size_t)b * SS * HH;
#pragma unroll
    for (int r = 0; r < 4; r++) {
        const int row = i0 + wy * 64 + r * 16 + quad * 4;
#pragma unroll
        for (int c = 0; c < 4; c++) {
            const int col = n0 + wx * 64 + c * 16 + m16;
#pragma unroll
            for (int reg = 0; reg < 4; reg++)
                Cb[(size_t)(row + reg) * HH + col] = acc[r][c][reg];
        }
    }
}

extern "C" void kernel_launch(void* const* d_in, const int* in_sizes, int n_in,
                              void* d_out, int out_size, void* d_ws, size_t ws_size,
                              hipStream_t stream) {
    const float* X = (const float*)d_in[0];   // [8,2048,1024]
    const float* W = (const float*)d_in[1];   // [1024,1024]
    float* ctx  = (float*)d_out;                           // [8,2048,1024]
    float* attn = ctx + (size_t)BB * SS * HH;              // [8,2048,2048]

    unsigned short* xT = (unsigned short*)d_ws;                        // 32 MB
    float* XW = (float*)((char*)d_ws + ((size_t)32 << 20));            // 64 MB
    unsigned short* attn_b = (unsigned short*)XW;                      // reuse after scores

    dim3 blk(256);
    transpose_cvt<<<dim3(HH / 64, SS / 64, BB), blk, 0, stream>>>(X, xT);
    gemm_xw     <<<dim3(HH / 64, SS / 64, BB), blk, 0, stream>>>(X, W, XW);
    gemm_scores <<<dim3(SS / 64, SS / 64, BB), blk, 0, stream>>>(XW, X, attn);
    softmax_rows<<<dim3(BB * SS), blk, 0, stream>>>(attn, attn_b);
    gemm_ctx_mfma<<<dim3(HH / 128, SS / 128, BB), blk, 0, stream>>>(attn_b, xT, ctx);
}

// Round 3
// 744.377 us; speedup vs baseline: 4.0693x; 2.8425x over previous
//
#include <hip/hip_runtime.h>
#include <hip/hip_bf16.h>

// B=8, S=2048, H=1024
//   x      -> x_hi + x_lo (bf16 split, fp32-emulation)          [ws]
//   W      -> Wt_hi + Wt_lo (transposed [n][k] bf16 split)      [ws]
//   xw     = x @ W        3-pass split-bf16 MFMA -> xw_hi/lo    [d_out ctx region, dead until end]
//   scores = xw @ x^T     3-pass split-bf16 MFMA (NT)           -> attn region of d_out (fp32)
//   attn   = softmax      in place + bf16 copy                  [ws, over dead x_lo/W]
//   ctx    = attn @ x     bf16 MFMA (NT via xT)                 -> ctx region (over dead xw)
//
// ws peak 96 MB (proven available in rounds 1-2):
//   [0,32M)  x_hi  -> later xT
//   [32,64M) x_lo  -> later attn_b[0:32M)
//   [64,66M) Wt_hi    [66,68M) Wt_lo   (attn_b extends to 96M over these)

#define BB 8
#define SS 2048
#define HH 1024

typedef __attribute__((ext_vector_type(8))) short bf16x8;
typedef __attribute__((ext_vector_type(4))) float f32x4;

__device__ __forceinline__ void async_load16(const void* gsrc, void* ldst) {
    typedef const unsigned int __attribute__((address_space(1)))* gp_t;
    typedef unsigned int __attribute__((address_space(3)))* lp_t;
    __builtin_amdgcn_global_load_lds((gp_t)gsrc, (lp_t)ldst, 16, 0, 0);
}

__device__ __forceinline__ unsigned short f2b(float f) {
    __hip_bfloat16 h = __float2bfloat16(f);
    return *(unsigned short*)&h;
}
__device__ __forceinline__ float b2f(unsigned short u) {
    __hip_bfloat16 h = *(__hip_bfloat16*)&u;
    return __bfloat162float(h);
}

// ----------------------------------------------------------- split x -> hi/lo bf16
__global__ __launch_bounds__(256) void split_x(const float* __restrict__ X,
                                               unsigned short* __restrict__ Xh,
                                               unsigned short* __restrict__ Xl) {
    const size_t i = ((size_t)blockIdx.x * 256 + threadIdx.x) * 8;
    float4 a = *(const float4*)(X + i);
    float4 b = *(const float4*)(X + i + 4);
    ushort4 h0, h1, l0, l1;
    float v, hf;
    v = a.x; h0.x = f2b(v); hf = b2f(h0.x); l0.x = f2b(v - hf);
    v = a.y; h0.y = f2b(v); hf = b2f(h0.y); l0.y = f2b(v - hf);
    v = a.z; h0.z = f2b(v); hf = b2f(h0.z); l0.z = f2b(v - hf);
    v = a.w; h0.w = f2b(v); hf = b2f(h0.w); l0.w = f2b(v - hf);
    v = b.x; h1.x = f2b(v); hf = b2f(h1.x); l1.x = f2b(v - hf);
    v = b.y; h1.y = f2b(v); hf = b2f(h1.y); l1.y = f2b(v - hf);
    v = b.z; h1.z = f2b(v); hf = b2f(h1.z); l1.z = f2b(v - hf);
    v = b.w; h1.w = f2b(v); hf = b2f(h1.w); l1.w = f2b(v - hf);
    *(ushort4*)(Xh + i) = h0; *(ushort4*)(Xh + i + 4) = h1;
    *(ushort4*)(Xl + i) = l0; *(ushort4*)(Xl + i + 4) = l1;
}

// ------------------------------------- W [k][n] -> Wt hi/lo [n][k] (bf16 split, transpose)
__global__ __launch_bounds__(256) void split_wT(const float* __restrict__ W,
                                                unsigned short* __restrict__ Th,
                                                unsigned short* __restrict__ Tl) {
    const int k0 = blockIdx.y * 64, n0 = blockIdx.x * 64;
    __shared__ float tile[64][65];
#pragma unroll
    for (int q = 0; q < 16; q++) {
        int idx = q * 256 + threadIdx.x;
        int r = idx >> 6, c = idx & 63;
        tile[r][c] = W[(size_t)(k0 + r) * HH + n0 + c];
    }
    __syncthreads();
#pragma unroll
    for (int q = 0; q < 16; q++) {
        int idx = q * 256 + threadIdx.x;
        int r = idx >> 6, c = idx & 63;            // r = n idx, c = k idx
        float v = tile[c][r];
        unsigned short h = f2b(v);
        Th[(size_t)(n0 + r) * HH + k0 + c] = h;
        Tl[(size_t)(n0 + r) * HH + k0 + c] = f2b(v - b2f(h));
    }
}

// ---------------- 3-pass split-bf16 MFMA GEMM (NT), 128x128 tile, BK=32, emits bf16 hi/lo
__global__ __launch_bounds__(256) void gemm_xw3(const unsigned short* __restrict__ Ah,
                                                const unsigned short* __restrict__ Al,
                                                const unsigned short* __restrict__ Bh,
                                                const unsigned short* __restrict__ Bl,
                                                unsigned short* __restrict__ Ch,
                                                unsigned short* __restrict__ Cl) {
    const int b = blockIdx.z;
    const int i0 = blockIdx.y * 128, n0 = blockIdx.x * 128;
    const unsigned short* A_h = Ah + (size_t)b * SS * HH;
    const unsigned short* A_l = Al + (size_t)b * SS * HH;

    __shared__ __align__(16) unsigned short AsH[128 * 32];
    __shared__ __align__(16) unsigned short AsL[128 * 32];
    __shared__ __align__(16) unsigned short BsH[128 * 32];
    __shared__ __align__(16) unsigned short BsL[128 * 32];

    const int tid = threadIdx.x;
    const int wave = tid >> 6, lane = tid & 63;
    const int m16 = lane & 15, quad = lane >> 4;
    const int wy = wave >> 1, wx = wave & 1;
    const int rowA = tid >> 2, kq = tid & 3;

    f32x4 acc[4][4] = {};

    for (int k0 = 0; k0 < HH; k0 += 32) {
        const size_t ga0 = (size_t)(i0 + rowA) * HH + k0 + kq * 8;
        const size_t ga1 = (size_t)(i0 + 64 + rowA) * HH + k0 + kq * 8;
        const size_t gb0 = (size_t)(n0 + rowA) * HH + k0 + kq * 8;
        const size_t gb1 = (size_t)(n0 + 64 + rowA) * HH + k0 + kq * 8;
        async_load16(A_h + ga0, (char*)AsH + wave * 1024);
        async_load16(A_h + ga1, (char*)AsH + 4096 + wave * 1024);
        async_load16(A_l + ga0, (char*)AsL + wave * 1024);
        async_load16(A_l + ga1, (char*)AsL + 4096 + wave * 1024);
        async_load16(Bh + gb0, (char*)BsH + wave * 1024);
        async_load16(Bh + gb1, (char*)BsH + 4096 + wave * 1024);
        async_load16(Bl + gb0, (char*)BsL + wave * 1024);
        async_load16(Bl + gb1, (char*)BsL + 4096 + wave * 1024);
        __syncthreads();

        const int offA = (wy * 64 + m16) * 32 + quad * 8;
        const int offB = (wx * 64 + m16) * 32 + quad * 8;
        bf16x8 ah[4], al[4], bh[4], bl[4];
#pragma unroll
        for (int r = 0; r < 4; r++) {
            ah[r] = *(const bf16x8*)(AsH + offA + r * 16 * 32);
            al[r] = *(const bf16x8*)(AsL + offA + r * 16 * 32);
        }
#pragma unroll
        for (int c = 0; c < 4; c++) {
            bh[c] = *(const bf16x8*)(BsH + offB + c * 16 * 32);
            bl[c] = *(const bf16x8*)(BsL + offB + c * 16 * 32);
        }
#pragma unroll
        for (int r = 0; r < 4; r++)
#pragma unroll
            for (int c = 0; c < 4; c++) {
                acc[r][c] = __builtin_amdgcn_mfma_f32_16x16x32_bf16(ah[r], bh[c], acc[r][c], 0, 0, 0);
                acc[r][c] = __builtin_amdgcn_mfma_f32_16x16x32_bf16(ah[r], bl[c], acc[r][c], 0, 0, 0);
                acc[r][c] = __builtin_amdgcn_mfma_f32_16x16x32_bf16(al[r], bh[c], acc[r][c], 0, 0, 0);
            }
        __syncthreads();
    }

    unsigned short* ChB = Ch + (size_t)b * SS * HH;
    unsigned short* ClB = Cl + (size_t)b * SS * HH;
#pragma unroll
    for (int r = 0; r < 4; r++) {
        const int row = i0 + wy * 64 + r * 16 + quad * 4;
#pragma unroll
        for (int c = 0; c < 4; c++) {
            const int col = n0 + wx * 64 + c * 16 + m16;
#pragma unroll
            for (int reg = 0; reg < 4; reg++) {
                float v = acc[r][c][reg];
                unsigned short h = f2b(v);
                ChB[(size_t)(row + reg) * HH + col] = h;
                ClB[(size_t)(row + reg) * HH + col] = f2b(v - b2f(h));
            }
        }
    }
}

// ---------------- scores = xw @ x^T (NT), 3-pass split-bf16 MFMA, fp32 out
__global__ __launch_bounds__(256) void gemm_sc3(const unsigned short* __restrict__ Ah,
                                                const unsigned short* __restrict__ Al,
                                                const unsigned short* __restrict__ Bh,
                                                const unsigned short* __restrict__ Bl,
                                                float* __restrict__ SC) {
    const int b = blockIdx.z;
    const int i0 = blockIdx.y * 128, j0 = blockIdx.x * 128;
    const unsigned short* A_h = Ah + (size_t)b * SS * HH;
    const unsigned short* A_l = Al + (size_t)b * SS * HH;
    const unsigned short* B_h = Bh + (size_t)b * SS * HH;
    const unsigned short* B_l = Bl + (size_t)b * SS * HH;

    __shared__ __align__(16) unsigned short AsH[128 * 32];
    __shared__ __align__(16) unsigned short AsL[128 * 32];
    __shared__ __align__(16) unsigned short BsH[128 * 32];
    __shared__ __align__(16) unsigned short BsL[128 * 32];

    const int tid = threadIdx.x;
    const int wave = tid >> 6, lane = tid & 63;
    const int m16 = lane & 15, quad = lane >> 4;
    const int wy = wave >> 1, wx = wave & 1;
    const int rowA = tid >> 2, kq = tid & 3;

    f32x4 acc[4][4] = {};

    for (int k0 = 0; k0 < HH; k0 += 32) {
        const size_t ga0 = (size_t)(i0 + rowA) * HH + k0 + kq * 8;
        const size_t ga1 = (size_t)(i0 + 64 + rowA) * HH + k0 + kq * 8;
        const size_t gb0 = (size_t)(j0 + rowA) * HH + k0 + kq * 8;
        const size_t gb1 = (size_t)(j0 + 64 + rowA) * HH + k0 + kq * 8;
        async_load16(A_h + ga0, (char*)AsH + wave * 1024);
        async_load16(A_h + ga1, (char*)AsH + 4096 + wave * 1024);
        async_load16(A_l + ga0, (char*)AsL + wave * 1024);
        async_load16(A_l + ga1, (char*)AsL + 4096 + wave * 1024);
        async_load16(B_h + gb0, (char*)BsH + wave * 1024);
        async_load16(B_h + gb1, (char*)BsH + 4096 + wave * 1024);
        async_load16(B_l + gb0, (char*)BsL + wave * 1024);
        async_load16(B_l + gb1, (char*)BsL + 4096 + wave * 1024);
        __syncthreads();

        const int offA = (wy * 64 + m16) * 32 + quad * 8;
        const int offB = (wx * 64 + m16) * 32 + quad * 8;
        bf16x8 ah[4], al[4], bh[4], bl[4];
#pragma unroll
        for (int r = 0; r < 4; r++) {
            ah[r] = *(const bf16x8*)(AsH + offA + r * 16 * 32);
            al[r] = *(const bf16x8*)(AsL + offA + r * 16 * 32);
        }
#pragma unroll
        for (int c = 0; c < 4; c++) {
            bh[c] = *(const bf16x8*)(BsH + offB + c * 16 * 32);
            bl[c] = *(const bf16x8*)(BsL + offB + c * 16 * 32);
        }
#pragma unroll
        for (int r = 0; r < 4; r++)
#pragma unroll
            for (int c = 0; c < 4; c++) {
                acc[r][c] = __builtin_amdgcn_mfma_f32_16x16x32_bf16(ah[r], bh[c], acc[r][c], 0, 0, 0);
                acc[r][c] = __builtin_amdgcn_mfma_f32_16x16x32_bf16(ah[r], bl[c], acc[r][c], 0, 0, 0);
                acc[r][c] = __builtin_amdgcn_mfma_f32_16x16x32_bf16(al[r], bh[c], acc[r][c], 0, 0, 0);
            }
        __syncthreads();
    }

    float* Cb = SC + (size_t)b * SS * SS;
#pragma unroll
    for (int r = 0; r < 4; r++) {
        const int row = i0 + wy * 64 + r * 16 + quad * 4;
#pragma unroll
        for (int c = 0; c < 4; c++) {
            const int col = j0 + wx * 64 + c * 16 + m16;
#pragma unroll
            for (int reg = 0; reg < 4; reg++)
                Cb[(size_t)(row + reg) * SS + col] = acc[r][c][reg];
        }
    }
}

// --------------------------- softmax in place (fp32) + bf16 copy for the MFMA ctx GEMM
__global__ __launch_bounds__(256) void softmax_rows(float* __restrict__ P,
                                                    unsigned short* __restrict__ Pb) {
    const size_t row = blockIdx.x;
    float4* p4 = (float4*)(P + row * SS);
    const int tid = threadIdx.x;
    float4 v0 = p4[tid], v1 = p4[tid + 256];
    float m = fmaxf(fmaxf(fmaxf(v0.x, v0.y), fmaxf(v0.z, v0.w)),
                    fmaxf(fmaxf(v1.x, v1.y), fmaxf(v1.z, v1.w)));
#pragma unroll
    for (int off = 32; off; off >>= 1) m = fmaxf(m, __shfl_xor(m, off));
    __shared__ float red[4];
    const int wid = tid >> 6, lane = tid & 63;
    if (lane == 0) red[wid] = m;
    __syncthreads();
    m = fmaxf(fmaxf(red[0], red[1]), fmaxf(red[2], red[3]));
    v0.x = __expf(v0.x - m); v0.y = __expf(v0.y - m);
    v0.z = __expf(v0.z - m); v0.w = __expf(v0.w - m);
    v1.x = __expf(v1.x - m); v1.y = __expf(v1.y - m);
    v1.z = __expf(v1.z - m); v1.w = __expf(v1.w - m);
    float s = v0.x + v0.y + v0.z + v0.w + v1.x + v1.y + v1.z + v1.w;
#pragma unroll
    for (int off = 32; off; off >>= 1) s += __shfl_xor(s, off);
    __syncthreads();
    if (lane == 0) red[wid] = s;
    __syncthreads();
    s = red[0] + red[1] + red[2] + red[3];
    const float inv = 1.0f / s;
    v0.x *= inv; v0.y *= inv; v0.z *= inv; v0.w *= inv;
    v1.x *= inv; v1.y *= inv; v1.z *= inv; v1.w *= inv;
    p4[tid] = v0;
    p4[tid + 256] = v1;
    ushort4* b4 = (ushort4*)(Pb + row * SS);
    ushort4 u0 = { f2b(v0.x), f2b(v0.y), f2b(v0.z), f2b(v0.w) };
    ushort4 u1 = { f2b(v1.x), f2b(v1.y), f2b(v1.z), f2b(v1.w) };
    b4[tid] = u0;
    b4[tid + 256] = u1;
}

// --------------------------------- x [B,S,H] fp32 -> xT [B,H,S] bf16 (for NT ctx GEMM)
__global__ __launch_bounds__(256) void transpose_cvt(const float* __restrict__ X,
                                                     unsigned short* __restrict__ XT) {
    const int b = blockIdx.z;
    const int t0 = blockIdx.y * 64;
    const int h0 = blockIdx.x * 64;
    __shared__ float tile[64][65];
    const float* Xb = X + (size_t)b * SS * HH;
    unsigned short* Tb = XT + (size_t)b * HH * SS;
#pragma unroll
    for (int q = 0; q < 16; q++) {
        int idx = q * 256 + threadIdx.x;
        int r = idx >> 6, c = idx & 63;
        tile[r][c] = Xb[(size_t)(t0 + r) * HH + h0 + c];
    }
    __syncthreads();
#pragma unroll
    for (int q = 0; q < 16; q++) {
        int idx = q * 256 + threadIdx.x;
        int r = idx >> 6, c = idx & 63;
        Tb[(size_t)(h0 + r) * SS + t0 + c] = f2b(tile[c][r]);
    }
}

// ----------------- ctx = attn @ x  (NT bf16 MFMA, m97 structure) — unchanged from round 2
__global__ __launch_bounds__(256) void gemm_ctx_mfma(const unsigned short* __restrict__ Ab,
                                                     const unsigned short* __restrict__ Bt,
                                                     float* __restrict__ C) {
    const int b = blockIdx.z;
    const int i0 = blockIdx.y * 128;
    const int n0 = blockIdx.x * 128;
    const unsigned short* A = Ab + (size_t)b * SS * SS;
    const unsigned short* B = Bt + (size_t)b * HH * SS;

    __shared__ __align__(16) unsigned short As[128 * 32];
    __shared__ __align__(16) unsigned short Bs[128 * 32];

    const int tid = threadIdx.x;
    const int wave = tid >> 6, lane = tid & 63;
    const int m16 = lane & 15, quad = lane >> 4;
    const int wy = wave >> 1, wx = wave & 1;
    const int rowA = tid >> 2, kq = tid & 3;

    f32x4 acc[4][4] = {};

    for (int k0 = 0; k0 < SS; k0 += 32) {
        async_load16(A + (size_t)(i0 + rowA) * SS + k0 + kq * 8, (char*)As + wave * 1024);
        async_load16(A + (size_t)(i0 + 64 + rowA) * SS + k0 + kq * 8, (char*)As + 4096 + wave * 1024);
        async_load16(B + (size_t)(n0 + rowA) * SS + k0 + kq * 8, (char*)Bs + wave * 1024);
        async_load16(B + (size_t)(n0 + 64 + rowA) * SS + k0 + kq * 8, (char*)Bs + 4096 + wave * 1024);
        __syncthreads();

        const unsigned short* pA = As + (wy * 64 + m16) * 32 + quad * 8;
        const unsigned short* pB = Bs + (wx * 64 + m16) * 32 + quad * 8;
        bf16x8 af[4], bfr[4];
#pragma unroll
        for (int r = 0; r < 4; r++) af[r] = *(const bf16x8*)(pA + r * 16 * 32);
#pragma unroll
        for (int c = 0; c < 4; c++) bfr[c] = *(const bf16x8*)(pB + c * 16 * 32);
#pragma unroll
        for (int r = 0; r < 4; r++)
#pragma unroll
            for (int c = 0; c < 4; c++)
                acc[r][c] = __builtin_amdgcn_mfma_f32_16x16x32_bf16(af[r], bfr[c], acc[r][c], 0, 0, 0);
        __syncthreads();
    }

    float* Cb = C + (size_t)b * SS * HH;
#pragma unroll
    for (int r = 0; r < 4; r++) {
        const int row = i0 + wy * 64 + r * 16 + quad * 4;
#pragma unroll
        for (int c = 0; c < 4; c++) {
            const int col = n0 + wx * 64 + c * 16 + m16;
#pragma unroll
            for (int reg = 0; reg < 4; reg++)
                Cb[(size_t)(row + reg) * HH + col] = acc[r][c][reg];
        }
    }
}

extern "C" void kernel_launch(void* const* d_in, const int* in_sizes, int n_in,
                              void* d_out, int out_size, void* d_ws, size_t ws_size,
                              hipStream_t stream) {
    const float* X = (const float*)d_in[0];   // [8,2048,1024]
    const float* W = (const float*)d_in[1];   // [1024,1024]
    float* ctx  = (float*)d_out;                            // [8,2048,1024]
    float* attn = ctx + (size_t)BB * SS * HH;               // [8,2048,2048]

    char* ws = (char*)d_ws;
    unsigned short* x_hi  = (unsigned short*)ws;                         // [0,32M)
    unsigned short* x_lo  = (unsigned short*)(ws + ((size_t)32 << 20));  // [32,64M)
    unsigned short* wt_hi = (unsigned short*)(ws + ((size_t)64 << 20));  // [64,66M)
    unsigned short* wt_lo = (unsigned short*)(ws + ((size_t)66 << 20));  // [66,68M)
    unsigned short* xT     = x_hi;                                       // after scores
    unsigned short* attn_b = x_lo;                                       // after scores (64M)

    // xw hi/lo live in the (dead-until-end) ctx region of d_out: 64 MB
    unsigned short* xw_hi = (unsigned short*)d_out;
    unsigned short* xw_lo = xw_hi + (size_t)BB * SS * HH;

    dim3 blk(256);
    split_x <<<dim3(BB * SS * HH / (8 * 256)), blk, 0, stream>>>(X, x_hi, x_lo);
    split_wT<<<dim3(HH / 64, HH / 64), blk, 0, stream>>>(W, wt_hi, wt_lo);
    gemm_xw3<<<dim3(HH / 128, SS / 128, BB), blk, 0, stream>>>(x_hi, x_lo, wt_hi, wt_lo, xw_hi, xw_lo);
    gemm_sc3<<<dim3(SS / 128, SS / 128, BB), blk, 0, stream>>>(xw_hi, xw_lo, x_hi, x_lo, attn);
    transpose_cvt<<<dim3(HH / 64, SS / 64, BB), blk, 0, stream>>>(X, xT);        // overwrites dead x_hi
    softmax_rows <<<dim3(BB * SS), blk, 0, stream>>>(attn, attn_b);              // overwrites dead x_lo/W
    gemm_ctx_mfma<<<dim3(HH / 128, SS / 128, BB), blk, 0, stream>>>(attn_b, xT, ctx); // overwrites dead xw
}

// Round 4
// 716.685 us; speedup vs baseline: 4.2265x; 1.0386x over previous
//
#include <hip/hip_runtime.h>
#include <hip/hip_bf16.h>

// B=8, S=2048, H=1024 — split-bf16 (fp32-emulation) MFMA pipeline.
//   x  -> x_hi/x_lo bf16; W -> Wt_hi/lo (transposed)
//   xw     = x @ W        3-pass split-bf16 MFMA -> xw_hi/lo (dead ctx region of d_out)
//   scores = xw @ x^T     3-pass split-bf16 MFMA -> attn region (fp32)
//   attn   = softmax      in place + bf16 copy
//   ctx    = attn @ x     1-pass bf16 MFMA (NT via xT)
//
// Round 4: XOR-swizzled LDS layout in all MFMA GEMMs. global_load_lds writes
// lane l -> slot l*16B (fixed), so we permute the SOURCE chunk per lane:
// slot (row r, chunk c') holds global chunk c'^((r>>1)&3); fragment reads use
// chunk' = quad^((m16>>1)&3). Each 16-lane phase then covers all 32 banks
// (2-way = free) instead of 8 banks (4-way serialize). Bit-identical math.

#define BB 8
#define SS 2048
#define HH 1024

typedef __attribute__((ext_vector_type(8))) short bf16x8;
typedef __attribute__((ext_vector_type(4))) float f32x4;

__device__ __forceinline__ void async_load16(const void* gsrc, void* ldst) {
    typedef const unsigned int __attribute__((address_space(1)))* gp_t;
    typedef unsigned int __attribute__((address_space(3)))* lp_t;
    __builtin_amdgcn_global_load_lds((gp_t)gsrc, (lp_t)ldst, 16, 0, 0);
}

__device__ __forceinline__ unsigned short f2b(float f) {
    __hip_bfloat16 h = __float2bfloat16(f);
    return *(unsigned short*)&h;
}
__device__ __forceinline__ float b2f(unsigned short u) {
    __hip_bfloat16 h = *(__hip_bfloat16*)&u;
    return __bfloat162float(h);
}

// ----------------------------------------------------------- split x -> hi/lo bf16
__global__ __launch_bounds__(256) void split_x(const float* __restrict__ X,
                                               unsigned short* __restrict__ Xh,
                                               unsigned short* __restrict__ Xl) {
    const size_t i = ((size_t)blockIdx.x * 256 + threadIdx.x) * 8;
    float4 a = *(const float4*)(X + i);
    float4 b = *(const float4*)(X + i + 4);
    ushort4 h0, h1, l0, l1;
    float v, hf;
    v = a.x; h0.x = f2b(v); hf = b2f(h0.x); l0.x = f2b(v - hf);
    v = a.y; h0.y = f2b(v); hf = b2f(h0.y); l0.y = f2b(v - hf);
    v = a.z; h0.z = f2b(v); hf = b2f(h0.z); l0.z = f2b(v - hf);
    v = a.w; h0.w = f2b(v); hf = b2f(h0.w); l0.w = f2b(v - hf);
    v = b.x; h1.x = f2b(v); hf = b2f(h1.x); l1.x = f2b(v - hf);
    v = b.y; h1.y = f2b(v); hf = b2f(h1.y); l1.y = f2b(v - hf);
    v = b.z; h1.z = f2b(v); hf = b2f(h1.z); l1.z = f2b(v - hf);
    v = b.w; h1.w = f2b(v); hf = b2f(h1.w); l1.w = f2b(v - hf);
    *(ushort4*)(Xh + i) = h0; *(ushort4*)(Xh + i + 4) = h1;
    *(ushort4*)(Xl + i) = l0; *(ushort4*)(Xl + i + 4) = l1;
}

// ------------------------------------- W [k][n] -> Wt hi/lo [n][k] (bf16 split, transpose)
__global__ __launch_bounds__(256) void split_wT(const float* __restrict__ W,
                                                unsigned short* __restrict__ Th,
                                                unsigned short* __restrict__ Tl) {
    const int k0 = blockIdx.y * 64, n0 = blockIdx.x * 64;
    __shared__ float tile[64][65];
#pragma unroll
    for (int q = 0; q < 16; q++) {
        int idx = q * 256 + threadIdx.x;
        int r = idx >> 6, c = idx & 63;
        tile[r][c] = W[(size_t)(k0 + r) * HH + n0 + c];
    }
    __syncthreads();
#pragma unroll
    for (int q = 0; q < 16; q++) {
        int idx = q * 256 + threadIdx.x;
        int r = idx >> 6, c = idx & 63;
        float v = tile[c][r];
        unsigned short h = f2b(v);
        Th[(size_t)(n0 + r) * HH + k0 + c] = h;
        Tl[(size_t)(n0 + r) * HH + k0 + c] = f2b(v - b2f(h));
    }
}

// ---------------- 3-pass split-bf16 MFMA GEMM (NT), 128x128 tile, BK=32, emits bf16 hi/lo
__global__ __launch_bounds__(256) void gemm_xw3(const unsigned short* __restrict__ Ah,
                                                const unsigned short* __restrict__ Al,
                                                const unsigned short* __restrict__ Bh,
                                                const unsigned short* __restrict__ Bl,
                                                unsigned short* __restrict__ Ch,
                                                unsigned short* __restrict__ Cl) {
    const int b = blockIdx.z;
    const int i0 = blockIdx.y * 128, n0 = blockIdx.x * 128;
    const unsigned short* A_h = Ah + (size_t)b * SS * HH;
    const unsigned short* A_l = Al + (size_t)b * SS * HH;

    __shared__ __align__(16) unsigned short AsH[128 * 32];
    __shared__ __align__(16) unsigned short AsL[128 * 32];
    __shared__ __align__(16) unsigned short BsH[128 * 32];
    __shared__ __align__(16) unsigned short BsL[128 * 32];

    const int tid = threadIdx.x;
    const int wave = tid >> 6, lane = tid & 63;
    const int m16 = lane & 15, quad = lane >> 4;
    const int wy = wave >> 1, wx = wave & 1;
    const int rowA = tid >> 2;
    const int kq = (tid & 3) ^ ((rowA >> 1) & 3);   // XOR-swizzled source chunk

    f32x4 acc[4][4] = {};

    for (int k0 = 0; k0 < HH; k0 += 32) {
        const size_t ga0 = (size_t)(i0 + rowA) * HH + k0 + kq * 8;
        const size_t ga1 = (size_t)(i0 + 64 + rowA) * HH + k0 + kq * 8;
        const size_t gb0 = (size_t)(n0 + rowA) * HH + k0 + kq * 8;
        const size_t gb1 = (size_t)(n0 + 64 + rowA) * HH + k0 + kq * 8;
        async_load16(A_h + ga0, (char*)AsH + wave * 1024);
        async_load16(A_h + ga1, (char*)AsH + 4096 + wave * 1024);
        async_load16(A_l + ga0, (char*)AsL + wave * 1024);
        async_load16(A_l + ga1, (char*)AsL + 4096 + wave * 1024);
        async_load16(Bh + gb0, (char*)BsH + wave * 1024);
        async_load16(Bh + gb1, (char*)BsH + 4096 + wave * 1024);
        async_load16(Bl + gb0, (char*)BsL + wave * 1024);
        async_load16(Bl + gb1, (char*)BsL + 4096 + wave * 1024);
        __syncthreads();

        const int cs = quad ^ ((m16 >> 1) & 3);     // swizzled read chunk
        const int offA = (wy * 64 + m16) * 32 + cs * 8;
        const int offB = (wx * 64 + m16) * 32 + cs * 8;
        bf16x8 ah[4], al[4], bh[4], bl[4];
#pragma unroll
        for (int r = 0; r < 4; r++) {
            ah[r] = *(const bf16x8*)(AsH + offA + r * 16 * 32);
            al[r] = *(const bf16x8*)(AsL + offA + r * 16 * 32);
        }
#pragma unroll
        for (int c = 0; c < 4; c++) {
            bh[c] = *(const bf16x8*)(BsH + offB + c * 16 * 32);
            bl[c] = *(const bf16x8*)(BsL + offB + c * 16 * 32);
        }
#pragma unroll
        for (int r = 0; r < 4; r++)
#pragma unroll
            for (int c = 0; c < 4; c++) {
                acc[r][c] = __builtin_amdgcn_mfma_f32_16x16x32_bf16(ah[r], bh[c], acc[r][c], 0, 0, 0);
                acc[r][c] = __builtin_amdgcn_mfma_f32_16x16x32_bf16(ah[r], bl[c], acc[r][c], 0, 0, 0);
                acc[r][c] = __builtin_amdgcn_mfma_f32_16x16x32_bf16(al[r], bh[c], acc[r][c], 0, 0, 0);
            }
        __syncthreads();
    }

    unsigned short* ChB = Ch + (size_t)b * SS * HH;
    unsigned short* ClB = Cl + (size_t)b * SS * HH;
#pragma unroll
    for (int r = 0; r < 4; r++) {
        const int row = i0 + wy * 64 + r * 16 + quad * 4;
#pragma unroll
        for (int c = 0; c < 4; c++) {
            const int col = n0 + wx * 64 + c * 16 + m16;
#pragma unroll
            for (int reg = 0; reg < 4; reg++) {
                float v = acc[r][c][reg];
                unsigned short h = f2b(v);
                ChB[(size_t)(row + reg) * HH + col] = h;
                ClB[(size_t)(row + reg) * HH + col] = f2b(v - b2f(h));
            }
        }
    }
}

// ---------------- scores = xw @ x^T (NT), 3-pass split-bf16 MFMA, fp32 out
__global__ __launch_bounds__(256) void gemm_sc3(const unsigned short* __restrict__ Ah,
                                                const unsigned short* __restrict__ Al,
                                                const unsigned short* __restrict__ Bh,
                                                const unsigned short* __restrict__ Bl,
                                                float* __restrict__ SC) {
    const int b = blockIdx.z;
    const int i0 = blockIdx.y * 128, j0 = blockIdx.x * 128;
    const unsigned short* A_h = Ah + (size_t)b * SS * HH;
    const unsigned short* A_l = Al + (size_t)b * SS * HH;
    const unsigned short* B_h = Bh + (size_t)b * SS * HH;
    const unsigned short* B_l = Bl + (size_t)b * SS * HH;

    __shared__ __align__(16) unsigned short AsH[128 * 32];
    __shared__ __align__(16) unsigned short AsL[128 * 32];
    __shared__ __align__(16) unsigned short BsH[128 * 32];
    __shared__ __align__(16) unsigned short BsL[128 * 32];

    const int tid = threadIdx.x;
    const int wave = tid >> 6, lane = tid & 63;
    const int m16 = lane & 15, quad = lane >> 4;
    const int wy = wave >> 1, wx = wave & 1;
    const int rowA = tid >> 2;
    const int kq = (tid & 3) ^ ((rowA >> 1) & 3);

    f32x4 acc[4][4] = {};

    for (int k0 = 0; k0 < HH; k0 += 32) {
        const size_t ga0 = (size_t)(i0 + rowA) * HH + k0 + kq * 8;
        const size_t ga1 = (size_t)(i0 + 64 + rowA) * HH + k0 + kq * 8;
        const size_t gb0 = (size_t)(j0 + rowA) * HH + k0 + kq * 8;
        const size_t gb1 = (size_t)(j0 + 64 + rowA) * HH + k0 + kq * 8;
        async_load16(A_h + ga0, (char*)AsH + wave * 1024);
        async_load16(A_h + ga1, (char*)AsH + 4096 + wave * 1024);
        async_load16(A_l + ga0, (char*)AsL + wave * 1024);
        async_load16(A_l + ga1, (char*)AsL + 4096 + wave * 1024);
        async_load16(B_h + gb0, (char*)BsH + wave * 1024);
        async_load16(B_h + gb1, (char*)BsH + 4096 + wave * 1024);
        async_load16(B_l + gb0, (char*)BsL + wave * 1024);
        async_load16(B_l + gb1, (char*)BsL + 4096 + wave * 1024);
        __syncthreads();

        const int cs = quad ^ ((m16 >> 1) & 3);
        const int offA = (wy * 64 + m16) * 32 + cs * 8;
        const int offB = (wx * 64 + m16) * 32 + cs * 8;
        bf16x8 ah[4], al[4], bh[4], bl[4];
#pragma unroll
        for (int r = 0; r < 4; r++) {
            ah[r] = *(const bf16x8*)(AsH + offA + r * 16 * 32);
            al[r] = *(const bf16x8*)(AsL + offA + r * 16 * 32);
        }
#pragma unroll
        for (int c = 0; c < 4; c++) {
            bh[c] = *(const bf16x8*)(BsH + offB + c * 16 * 32);
            bl[c] = *(const bf16x8*)(BsL + offB + c * 16 * 32);
        }
#pragma unroll
        for (int r = 0; r < 4; r++)
#pragma unroll
            for (int c = 0; c < 4; c++) {
                acc[r][c] = __builtin_amdgcn_mfma_f32_16x16x32_bf16(ah[r], bh[c], acc[r][c], 0, 0, 0);
                acc[r][c] = __builtin_amdgcn_mfma_f32_16x16x32_bf16(ah[r], bl[c], acc[r][c], 0, 0, 0);
                acc[r][c] = __builtin_amdgcn_mfma_f32_16x16x32_bf16(al[r], bh[c], acc[r][c], 0, 0, 0);
            }
        __syncthreads();
    }

    float* Cb = SC + (size_t)b * SS * SS;
#pragma unroll
    for (int r = 0; r < 4; r++) {
        const int row = i0 + wy * 64 + r * 16 + quad * 4;
#pragma unroll
        for (int c = 0; c < 4; c++) {
            const int col = j0 + wx * 64 + c * 16 + m16;
#pragma unroll
            for (int reg = 0; reg < 4; reg++)
                Cb[(size_t)(row + reg) * SS + col] = acc[r][c][reg];
        }
    }
}

// --------------------------- softmax in place (fp32) + bf16 copy for the MFMA ctx GEMM
__global__ __launch_bounds__(256) void softmax_rows(float* __restrict__ P,
                                                    unsigned short* __restrict__ Pb) {
    const size_t row = blockIdx.x;
    float4* p4 = (float4*)(P + row * SS);
    const int tid = threadIdx.x;
    float4 v0 = p4[tid], v1 = p4[tid + 256];
    float m = fmaxf(fmaxf(fmaxf(v0.x, v0.y), fmaxf(v0.z, v0.w)),
                    fmaxf(fmaxf(v1.x, v1.y), fmaxf(v1.z, v1.w)));
#pragma unroll
    for (int off = 32; off; off >>= 1) m = fmaxf(m, __shfl_xor(m, off));
    __shared__ float red[4];
    const int wid = tid >> 6, lane = tid & 63;
    if (lane == 0) red[wid] = m;
    __syncthreads();
    m = fmaxf(fmaxf(red[0], red[1]), fmaxf(red[2], red[3]));
    v0.x = __expf(v0.x - m); v0.y = __expf(v0.y - m);
    v0.z = __expf(v0.z - m); v0.w = __expf(v0.w - m);
    v1.x = __expf(v1.x - m); v1.y = __expf(v1.y - m);
    v1.z = __expf(v1.z - m); v1.w = __expf(v1.w - m);
    float s = v0.x + v0.y + v0.z + v0.w + v1.x + v1.y + v1.z + v1.w;
#pragma unroll
    for (int off = 32; off; off >>= 1) s += __shfl_xor(s, off);
    __syncthreads();
    if (lane == 0) red[wid] = s;
    __syncthreads();
    s = red[0] + red[1] + red[2] + red[3];
    const float inv = 1.0f / s;
    v0.x *= inv; v0.y *= inv; v0.z *= inv; v0.w *= inv;
    v1.x *= inv; v1.y *= inv; v1.z *= inv; v1.w *= inv;
    p4[tid] = v0;
    p4[tid + 256] = v1;
    ushort4* b4 = (ushort4*)(Pb + row * SS);
    ushort4 u0 = { f2b(v0.x), f2b(v0.y), f2b(v0.z), f2b(v0.w) };
    ushort4 u1 = { f2b(v1.x), f2b(v1.y), f2b(v1.z), f2b(v1.w) };
    b4[tid] = u0;
    b4[tid + 256] = u1;
}

// --------------------------------- x [B,S,H] fp32 -> xT [B,H,S] bf16 (for NT ctx GEMM)
__global__ __launch_bounds__(256) void transpose_cvt(const float* __restrict__ X,
                                                     unsigned short* __restrict__ XT) {
    const int b = blockIdx.z;
    const int t0 = blockIdx.y * 64;
    const int h0 = blockIdx.x * 64;
    __shared__ float tile[64][65];
    const float* Xb = X + (size_t)b * SS * HH;
    unsigned short* Tb = XT + (size_t)b * HH * SS;
#pragma unroll
    for (int q = 0; q < 16; q++) {
        int idx = q * 256 + threadIdx.x;
        int r = idx >> 6, c = idx & 63;
        tile[r][c] = Xb[(size_t)(t0 + r) * HH + h0 + c];
    }
    __syncthreads();
#pragma unroll
    for (int q = 0; q < 16; q++) {
        int idx = q * 256 + threadIdx.x;
        int r = idx >> 6, c = idx & 63;
        Tb[(size_t)(h0 + r) * SS + t0 + c] = f2b(tile[c][r]);
    }
}

// ----------------- ctx = attn @ x  (NT bf16 MFMA, swizzled LDS)
__global__ __launch_bounds__(256) void gemm_ctx_mfma(const unsigned short* __restrict__ Ab,
                                                     const unsigned short* __restrict__ Bt,
                                                     float* __restrict__ C) {
    const int b = blockIdx.z;
    const int i0 = blockIdx.y * 128;
    const int n0 = blockIdx.x * 128;
    const unsigned short* A = Ab + (size_t)b * SS * SS;
    const unsigned short* B = Bt + (size_t)b * HH * SS;

    __shared__ __align__(16) unsigned short As[128 * 32];
    __shared__ __align__(16) unsigned short Bs[128 * 32];

    const int tid = threadIdx.x;
    const int wave = tid >> 6, lane = tid & 63;
    const int m16 = lane & 15, quad = lane >> 4;
    const int wy = wave >> 1, wx = wave & 1;
    const int rowA = tid >> 2;
    const int kq = (tid & 3) ^ ((rowA >> 1) & 3);

    f32x4 acc[4][4] = {};

    for (int k0 = 0; k0 < SS; k0 += 32) {
        async_load16(A + (size_t)(i0 + rowA) * SS + k0 + kq * 8, (char*)As + wave * 1024);
        async_load16(A + (size_t)(i0 + 64 + rowA) * SS + k0 + kq * 8, (char*)As + 4096 + wave * 1024);
        async_load16(B + (size_t)(n0 + rowA) * SS + k0 + kq * 8, (char*)Bs + wave * 1024);
        async_load16(B + (size_t)(n0 + 64 + rowA) * SS + k0 + kq * 8, (char*)Bs + 4096 + wave * 1024);
        __syncthreads();

        const int cs = quad ^ ((m16 >> 1) & 3);
        const unsigned short* pA = As + (wy * 64 + m16) * 32 + cs * 8;
        const unsigned short* pB = Bs + (wx * 64 + m16) * 32 + cs * 8;
        bf16x8 af[4], bfr[4];
#pragma unroll
        for (int r = 0; r < 4; r++) af[r] = *(const bf16x8*)(pA + r * 16 * 32);
#pragma unroll
        for (int c = 0; c < 4; c++) bfr[c] = *(const bf16x8*)(pB + c * 16 * 32);
#pragma unroll
        for (int r = 0; r < 4; r++)
#pragma unroll
            for (int c = 0; c < 4; c++)
                acc[r][c] = __builtin_amdgcn_mfma_f32_16x16x32_bf16(af[r], bfr[c], acc[r][c], 0, 0, 0);
        __syncthreads();
    }

    float* Cb = C + (size_t)b * SS * HH;
#pragma unroll
    for (int r = 0; r < 4; r++) {
        const int row = i0 + wy * 64 + r * 16 + quad * 4;
#pragma unroll
        for (int c = 0; c < 4; c++) {
            const int col = n0 + wx * 64 + c * 16 + m16;
#pragma unroll
            for (int reg = 0; reg < 4; reg++)
                Cb[(size_t)(row + reg) * HH + col] = acc[r][c][reg];
        }
    }
}

extern "C" void kernel_launch(void* const* d_in, const int* in_sizes, int n_in,
                              void* d_out, int out_size, void* d_ws, size_t ws_size,
                              hipStream_t stream) {
    const float* X = (const float*)d_in[0];   // [8,2048,1024]
    const float* W = (const float*)d_in[1];   // [1024,1024]
    float* ctx  = (float*)d_out;                            // [8,2048,1024]
    float* attn = ctx + (size_t)BB * SS * HH;               // [8,2048,2048]

    char* ws = (char*)d_ws;
    unsigned short* x_hi  = (unsigned short*)ws;                         // [0,32M)
    unsigned short* x_lo  = (unsigned short*)(ws + ((size_t)32 << 20));  // [32,64M)
    unsigned short* wt_hi = (unsigned short*)(ws + ((size_t)64 << 20));  // [64,66M)
    unsigned short* wt_lo = (unsigned short*)(ws + ((size_t)66 << 20));  // [66,68M)
    unsigned short* xT     = x_hi;                                       // after scores
    unsigned short* attn_b = x_lo;                                       // after scores

    unsigned short* xw_hi = (unsigned short*)d_out;   // dead ctx region until final GEMM
    unsigned short* xw_lo = xw_hi + (size_t)BB * SS * HH;

    dim3 blk(256);
    split_x <<<dim3(BB * SS * HH / (8 * 256)), blk, 0, stream>>>(X, x_hi, x_lo);
    split_wT<<<dim3(HH / 64, HH / 64), blk, 0, stream>>>(W, wt_hi, wt_lo);
    gemm_xw3<<<dim3(HH / 128, SS / 128, BB), blk, 0, stream>>>(x_hi, x_lo, wt_hi, wt_lo, xw_hi, xw_lo);
    gemm_sc3<<<dim3(SS / 128, SS / 128, BB), blk, 0, stream>>>(xw_hi, xw_lo, x_hi, x_lo, attn);
    transpose_cvt<<<dim3(HH / 64, SS / 64, BB), blk, 0, stream>>>(X, xT);
    softmax_rows <<<dim3(BB * SS), blk, 0, stream>>>(attn, attn_b);
    gemm_ctx_mfma<<<dim3(HH / 128, SS / 128, BB), blk, 0, stream>>>(attn_b, xT, ctx);
}